// Round 9
// baseline (607.352 us; speedup 1.0000x reference)
//
#include <hip/hip_runtime.h>

typedef _Float16 h16;
typedef __attribute__((ext_vector_type(8))) _Float16 half8;
typedef __attribute__((ext_vector_type(4))) _Float16 half4;
typedef __attribute__((ext_vector_type(4))) float f32x4;
typedef __attribute__((ext_vector_type(16))) float f32x16;

// weight fragment offsets in d_ws (fp16 elements) — same conv format as R4..R8
constexpr size_t OFF_P0 = 0;        // [64 ][256]
constexpr size_t OFF_P1 = 16384;    // [256][256]
constexpr size_t OFF_P2 = 81920;
constexpr size_t OFF_P3 = 147456;
constexpr size_t OFF_P4 = 212992;
constexpr size_t OFF_P5 = 278528;   // [320][256], ROTATED: rows 0..255 = h-part, 256..319 = ep-part
constexpr size_t OFF_P6 = 360448;
constexpr size_t OFF_P7 = 425984;
constexpr size_t OFF_FEAT = 491520; // [256][256]
constexpr size_t OFF_VIEWS = 557056;// [288][128] (rows 0..255 feat, 256..282 ev, 283..287 zero)

__device__ __forceinline__ f32x16 mfma32(half8 a, half8 b, f32x16 c) {
  return __builtin_amdgcn_mfma_f32_32x32x16_f16(a, b, c, 0, 0, 0);
}
__device__ __forceinline__ half8 ldfrag(const h16* __restrict__ base, int frag, int l) {
  return *(const half8*)(base + (size_t)frag * 512 + (size_t)l * 8);
}
__device__ __forceinline__ half8 ldsfrag(const h16* __restrict__ base, int frag, int l) {
  return *(const half8*)(base + frag * 512 + l * 8);
}

// fp32 [K][N] row-major -> pre-swizzled fp16 fragments for 32x32x16 (unchanged).
__global__ void convw_kernel(const float* __restrict__ src, h16* __restrict__ dst,
                             int Ksrc, int N, int Kp, int p, int npad, int rot) {
  int t = blockIdx.x * 256 + threadIdx.x;
  int nfrags = (Kp >> 4) * (N >> 5);
  int frag = t >> 6;
  if (frag >= nfrags) return;
  int l = t & 63;
  int ntiles = N >> 5;
  int kt = frag / ntiles;
  int nt = frag - kt * ntiles;
  int col = nt * 32 + (l & 31);
  int kbase = kt * 16 + (l >> 5) * 8;
  half8 v;
#pragma unroll
  for (int j = 0; j < 8; ++j) {
    int pr = kbase + j + rot;
    if (pr >= Kp) pr -= Kp;
    float x = 0.f;
    if (pr < p) {
      x = src[(size_t)pr * N + col];
    } else if (pr >= p + npad) {
      int r = pr - npad;
      if (r < Ksrc) x = src[(size_t)r * N + col];
    }
    v[j] = (h16)x;
  }
  *(half8*)(dst + (size_t)frag * 512 + (size_t)l * 8) = v;
}

struct Params {
  const float* pts;
  const float* views;
  const h16* wf;
  const float* pb[8];
  const float* views_b;
  const float* feat_b;
  const float* alpha_w;
  const float* alpha_b;
  const float* rgb_w;
  const float* rgb_b;
  float* out;
};

// Epilogue: one 32x32 tile -> frag-major LDS (HW-verified layout, R6..R8).
// Element (row,col): frag=(row>>5)*16+(col>>4), slot=(row&31)+32*((col>>3)&1), elem=col&7.
template <bool RELU>
__device__ __forceinline__ void epiW(h16* __restrict__ Y, const f32x16& A,
                                     int rt, int ct, const float* __restrict__ bias,
                                     int lr, int lh) {
#pragma unroll
  for (int g = 0; g < 4; ++g) {
    int col0 = ct * 32 + g * 8 + lh * 4;
    f32x4 bv = *(const f32x4*)(bias + col0);
    half4 pk;
#pragma unroll
    for (int i = 0; i < 4; ++i) {
      float v = A[g * 4 + i] + bv[i];
      if (RELU) v = fmaxf(v, 0.f);
      pk[i] = (h16)v;
    }
    *(half4*)(Y + (rt * 16 + ct * 2 + (g >> 1)) * 512 + ((g & 1) * 32 + lr) * 8 + lh * 4) = pk;
  }
}

// embed value for column c given a point (x0,x1,x2)
__device__ __forceinline__ float embed_col(int c, float x0, float x1, float x2) {
  if (c < 3) return c == 0 ? x0 : (c == 1 ? x1 : x2);
  if (c >= 63) return 0.f;
  int t = c - 3;
  int f = t / 6, rem = t - f * 6;
  int d = rem >= 3 ? rem - 3 : rem;
  float x = (d == 0 ? x0 : (d == 1 ? x1 : x2)) * (float)(1 << f);
  return (rem < 3) ? sinf(x) : cosf(x);
}

// compute this wave-lane's 4 ep fragments (rows rt*32+lr, k-cols kt*16+lh*8+j)
__device__ __forceinline__ void make_epf(half8 (&epf)[4], float x0, float x1, float x2, int lh) {
#pragma unroll
  for (int kt = 0; kt < 4; ++kt) {
    half8 v;
#pragma unroll
    for (int j = 0; j < 8; ++j)
      v[j] = (h16)embed_col(kt * 16 + lh * 8 + j, x0, x1, x2);
    epf[kt] = v;
  }
}

// One trunk layer, M=128, N=256, in-place on h (frag-major [rt*16+kt], rt 0..3).
// Wave (rt = w&3, ch = w>>2): 1 row-tile x 4 col-tiles (ct0 = ch*4).
// EXTEP (L5): 4 extra kts from register ep frags (recomputed by caller).
template <bool RELU, bool EXTEP>
__device__ __forceinline__ void layerT(h16* __restrict__ h,
                                       const h16* __restrict__ wcur,
                                       const float* __restrict__ bias,
                                       const half8* epf,
                                       int rt, int ct0, int l, int lr, int lh) {
  f32x16 a0 = (f32x16)0.f, a1 = (f32x16)0.f, a2 = (f32x16)0.f, a3 = (f32x16)0.f;
#pragma unroll
  for (int kt = 0; kt < 16; ++kt) {
    half8 x = ldsfrag(h, rt * 16 + kt, l);
    half8 w0 = ldfrag(wcur, kt * 8 + ct0 + 0, l);
    half8 w1 = ldfrag(wcur, kt * 8 + ct0 + 1, l);
    half8 w2 = ldfrag(wcur, kt * 8 + ct0 + 2, l);
    half8 w3 = ldfrag(wcur, kt * 8 + ct0 + 3, l);
    a0 = mfma32(w0, x, a0);
    a1 = mfma32(w1, x, a1);
    a2 = mfma32(w2, x, a2);
    a3 = mfma32(w3, x, a3);
  }
  if (EXTEP) {
#pragma unroll
    for (int j = 0; j < 4; ++j) {
      half8 x = epf[j];
      half8 w0 = ldfrag(wcur, (16 + j) * 8 + ct0 + 0, l);
      half8 w1 = ldfrag(wcur, (16 + j) * 8 + ct0 + 1, l);
      half8 w2 = ldfrag(wcur, (16 + j) * 8 + ct0 + 2, l);
      half8 w3 = ldfrag(wcur, (16 + j) * 8 + ct0 + 3, l);
      a0 = mfma32(w0, x, a0);
      a1 = mfma32(w1, x, a1);
      a2 = mfma32(w2, x, a2);
      a3 = mfma32(w3, x, a3);
    }
  }
  __syncthreads();  // all reads of h complete before overwrite
  epiW<RELU>(h, a0, rt, ct0 + 0, bias, lr, lh);
  epiW<RELU>(h, a1, rt, ct0 + 1, bias, lr, lh);
  epiW<RELU>(h, a2, rt, ct0 + 2, bias, lr, lh);
  epiW<RELU>(h, a3, rt, ct0 + 3, bias, lr, lh);
  __syncthreads();
}

__global__ __launch_bounds__(512, 4) void nerf_kernel(Params P) {
  __shared__ __align__(16) h16 h[64 * 512];   // 64 KB, frag-major [rt*16 + kt]
  __shared__ __align__(16) h16 evp[64];       // 2 rays x 32
  __shared__ float alpha_s[128];

  const int tid = threadIdx.x;
  const int w = tid >> 6, l = tid & 63;
  const int lr = l & 31, lh = l >> 5;
  const int rt = w & 3, ch = w >> 2;
  const int ct0 = ch * 4;
  const h16* wf = P.wf;
  const size_t row_base = (size_t)blockIdx.x * 128;

  // per-lane point (row = rt*32 + lr); kept live (3 regs) for L0 + L5 recompute
  const float* ps = P.pts + (row_base + rt * 32 + lr) * 3;
  const float x0 = ps[0], x1 = ps[1], x2 = ps[2];

  // views embedding (2 rays per block)
  if (tid < 64) {
    const int r = tid >> 5, idx = tid & 31;
    float v = 0.f;
    if (idx < 27) {
      if (idx < 3) {
        v = P.views[((size_t)blockIdx.x * 2 + r) * 3 + idx];
      } else {
        const int f = (idx - 3) / 6, rem = (idx - 3) % 6, d = rem % 3;
        const float x = P.views[((size_t)blockIdx.x * 2 + r) * 3 + d] * (float)(1 << f);
        v = (rem < 3) ? sinf(x) : cosf(x);
      }
    }
    evp[tid] = (h16)v;
  }

  // ---- L0: K=64 from transient register ep frags ----
  {
    half8 epf[4];
    make_epf(epf, x0, x1, x2, lh);
    f32x16 a0 = (f32x16)0.f, a1 = (f32x16)0.f, a2 = (f32x16)0.f, a3 = (f32x16)0.f;
#pragma unroll
    for (int kt = 0; kt < 4; ++kt) {
      half8 x = epf[kt];
      half8 w0 = ldfrag(wf + OFF_P0, kt * 8 + ct0 + 0, l);
      half8 w1 = ldfrag(wf + OFF_P0, kt * 8 + ct0 + 1, l);
      half8 w2 = ldfrag(wf + OFF_P0, kt * 8 + ct0 + 2, l);
      half8 w3 = ldfrag(wf + OFF_P0, kt * 8 + ct0 + 3, l);
      a0 = mfma32(w0, x, a0);
      a1 = mfma32(w1, x, a1);
      a2 = mfma32(w2, x, a2);
      a3 = mfma32(w3, x, a3);
    }
    epiW<true>(h, a0, rt, ct0 + 0, P.pb[0], lr, lh);
    epiW<true>(h, a1, rt, ct0 + 1, P.pb[0], lr, lh);
    epiW<true>(h, a2, rt, ct0 + 2, P.pb[0], lr, lh);
    epiW<true>(h, a3, rt, ct0 + 3, P.pb[0], lr, lh);
    __syncthreads();
  }

  // ---- trunk L1..L7 (in-place) ----
  layerT<true, false>(h, wf + OFF_P1, P.pb[1], nullptr, rt, ct0, l, lr, lh);
  layerT<true, false>(h, wf + OFF_P2, P.pb[2], nullptr, rt, ct0, l, lr, lh);
  layerT<true, false>(h, wf + OFF_P3, P.pb[3], nullptr, rt, ct0, l, lr, lh);
  layerT<true, false>(h, wf + OFF_P4, P.pb[4], nullptr, rt, ct0, l, lr, lh);
  {
    half8 epf[4];
    make_epf(epf, x0, x1, x2, lh);  // transient recompute for the skip concat
    layerT<true, true>(h, wf + OFF_P5, P.pb[5], epf, rt, ct0, l, lr, lh);  // K=320
  }
  layerT<true, false>(h, wf + OFF_P6, P.pb[6], nullptr, rt, ct0, l, lr, lh);
  layerT<true, false>(h, wf + OFF_P7, P.pb[7], nullptr, rt, ct0, l, lr, lh);

  // ---- alpha = h @ alpha_w + alpha_b (before feature overwrites h) ----
  {
    const int s = tid >> 2, q = tid & 3;
    float sum = 0.f;
#pragma unroll
    for (int j = 0; j < 8; ++j) {
      int k0 = q * 64 + j * 8;
      half8 hv = *(const half8*)(h + ((s >> 5) * 16 + (k0 >> 4)) * 512 +
                                 ((s & 31) + 32 * ((k0 >> 3) & 1)) * 8);
      f32x4 w0 = *(const f32x4*)(P.alpha_w + k0);
      f32x4 w1 = *(const f32x4*)(P.alpha_w + k0 + 4);
      sum += (float)hv[0] * w0[0] + (float)hv[1] * w0[1] + (float)hv[2] * w0[2] + (float)hv[3] * w0[3];
      sum += (float)hv[4] * w1[0] + (float)hv[5] * w1[1] + (float)hv[6] * w1[2] + (float)hv[7] * w1[3];
    }
    sum += __shfl_xor(sum, 1);
    sum += __shfl_xor(sum, 2);
    if (q == 0) alpha_s[s] = sum + P.alpha_b[0];
  }

  // ---- feature = h @ feat_w + feat_b (no relu), in place ----
  layerT<false, false>(h, wf + OFF_FEAT, P.feat_b, nullptr, rt, ct0, l, lr, lh);

  // ---- h2 = relu([feature, ev] @ views_w + views_b) -> h cols 0..127 ----
  // wave: rt = w&3, col-tiles {2ch, 2ch+1}. K=288 (16 h-kt + 2 evp-kt).
  {
    const int cv0 = ch * 2;
    const h16* wV = wf + OFF_VIEWS;
    f32x16 b0 = (f32x16)0.f, b1 = (f32x16)0.f;
#pragma unroll
    for (int kt = 0; kt < 16; ++kt) {
      half8 x = ldsfrag(h, rt * 16 + kt, l);
      half8 w0 = ldfrag(wV, kt * 4 + cv0 + 0, l);
      half8 w1 = ldfrag(wV, kt * 4 + cv0 + 1, l);
      b0 = mfma32(w0, x, b0);
      b1 = mfma32(w1, x, b1);
    }
#pragma unroll
    for (int kt = 16; kt < 18; ++kt) {
      half8 x = *(const half8*)(evp + (rt >> 1) * 32 + (kt - 16) * 16 + lh * 8);
      half8 w0 = ldfrag(wV, kt * 4 + cv0 + 0, l);
      half8 w1 = ldfrag(wV, kt * 4 + cv0 + 1, l);
      b0 = mfma32(w0, x, b0);
      b1 = mfma32(w1, x, b1);
    }
    __syncthreads();
    epiW<true>(h, b0, rt, cv0 + 0, P.views_b, lr, lh);
    epiW<true>(h, b1, rt, cv0 + 1, P.views_b, lr, lh);
    __syncthreads();
  }

  // ---- rgb + output ----
  {
    const int s = tid >> 2, q = tid & 3;
    float r0 = 0.f, r1 = 0.f, r2 = 0.f;
#pragma unroll
    for (int j = 0; j < 4; ++j) {
      int k0 = q * 32 + j * 8;
      half8 hv = *(const half8*)(h + ((s >> 5) * 16 + (k0 >> 4)) * 512 +
                                 ((s & 31) + 32 * ((k0 >> 3) & 1)) * 8);
#pragma unroll
      for (int i = 0; i < 8; ++i) {
        const float f = (float)hv[i];
        r0 += f * P.rgb_w[(k0 + i) * 3 + 0];
        r1 += f * P.rgb_w[(k0 + i) * 3 + 1];
        r2 += f * P.rgb_w[(k0 + i) * 3 + 2];
      }
    }
    r0 += __shfl_xor(r0, 1); r0 += __shfl_xor(r0, 2);
    r1 += __shfl_xor(r1, 1); r1 += __shfl_xor(r1, 2);
    r2 += __shfl_xor(r2, 1); r2 += __shfl_xor(r2, 2);
    if (q == 0) {
      float4 o;
      o.x = r0 + P.rgb_b[0];
      o.y = r1 + P.rgb_b[1];
      o.z = r2 + P.rgb_b[2];
      o.w = alpha_s[s];
      *(float4*)(P.out + (row_base + s) * 4) = o;
    }
  }
}

extern "C" void kernel_launch(void* const* d_in, const int* in_sizes, int n_in,
                              void* d_out, int out_size, void* d_ws, size_t ws_size,
                              hipStream_t stream) {
  h16* wsw = (h16*)d_ws;
  auto conv = [&](int idx, int Ksrc, int N, int Kp, int p, int npad, int rot, size_t off) {
    int nfrags = (Kp / 16) * (N / 32);
    int total = nfrags * 64;
    convw_kernel<<<(total + 255) / 256, 256, 0, stream>>>(
        (const float*)d_in[idx], wsw + off, Ksrc, N, Kp, p, npad, rot);
  };
  conv(2, 63, 256, 64, 63, 1, 0, OFF_P0);
  conv(4, 256, 256, 256, 256, 0, 0, OFF_P1);
  conv(6, 256, 256, 256, 256, 0, 0, OFF_P2);
  conv(8, 256, 256, 256, 256, 0, 0, OFF_P3);
  conv(10, 256, 256, 256, 256, 0, 0, OFF_P4);
  conv(12, 319, 256, 320, 63, 1, 64, OFF_P5);   // rotated: h-part first
  conv(14, 256, 256, 256, 256, 0, 0, OFF_P6);
  conv(16, 256, 256, 256, 256, 0, 0, OFF_P7);
  conv(20, 256, 256, 256, 256, 0, 0, OFF_FEAT);
  conv(18, 283, 128, 288, 283, 5, 0, OFF_VIEWS);

  Params P;
  P.pts = (const float*)d_in[0];
  P.views = (const float*)d_in[1];
  P.wf = wsw;
  for (int i = 0; i < 8; ++i) P.pb[i] = (const float*)d_in[3 + 2 * i];
  P.views_b = (const float*)d_in[19];
  P.feat_b = (const float*)d_in[21];
  P.alpha_w = (const float*)d_in[22];
  P.alpha_b = (const float*)d_in[23];
  P.rgb_w = (const float*)d_in[24];
  P.rgb_b = (const float*)d_in[25];
  P.out = (float*)d_out;

  nerf_kernel<<<2048, 512, 0, stream>>>(P);
}

// Round 10
// 377.029 us; speedup vs baseline: 1.6109x; 1.6109x over previous
//
#include <hip/hip_runtime.h>

typedef _Float16 h16;
typedef __attribute__((ext_vector_type(8))) _Float16 half8;
typedef __attribute__((ext_vector_type(4))) _Float16 half4;
typedef __attribute__((ext_vector_type(4))) float f32x4;
typedef __attribute__((ext_vector_type(16))) float f32x16;

#define LDH 264   // h-buffer row stride in fp16 elems (256 + 8 pad)
#define LDE 72    // ep-buffer row stride (64 + 8 pad)

// weight fragment offsets in d_ws (fp16 elements)
constexpr size_t OFF_P0 = 0;        // [64 ][256]
constexpr size_t OFF_P1 = 16384;    // [256][256]
constexpr size_t OFF_P2 = 81920;
constexpr size_t OFF_P3 = 147456;
constexpr size_t OFF_P4 = 212992;
constexpr size_t OFF_P5 = 278528;   // [320][256] (zero row inserted at 63)
constexpr size_t OFF_P6 = 360448;
constexpr size_t OFF_P7 = 425984;
constexpr size_t OFF_FEAT = 491520; // [256][256]
constexpr size_t OFF_VIEWS = 557056;// [288][128] (zero rows 283..287)

__device__ __forceinline__ f32x16 mfma32(half8 a, half8 b, f32x16 c) {
  return __builtin_amdgcn_mfma_f32_32x32x16_f16(a, b, c, 0, 0, 0);
}

// fp32 [K][N] row-major -> pre-swizzled fp16 fragments for 32x32x16.
// Fragment (kt,nt): lane l's 8 fp16 = B[kt*16+(l>>5)*8+j][nt*32+(l&31)].
__global__ void convw_kernel(const float* __restrict__ src, h16* __restrict__ dst,
                             int Ksrc, int N, int Kp, int p, int npad) {
  int t = blockIdx.x * 256 + threadIdx.x;
  int nfrags = (Kp >> 4) * (N >> 5);
  int frag = t >> 6;
  if (frag >= nfrags) return;
  int l = t & 63;
  int ntiles = N >> 5;
  int kt = frag / ntiles;
  int nt = frag - kt * ntiles;
  int col = nt * 32 + (l & 31);
  int kbase = kt * 16 + (l >> 5) * 8;
  half8 v;
#pragma unroll
  for (int j = 0; j < 8; ++j) {
    int k = kbase + j;
    float x = 0.f;
    if (k < p) {
      x = src[(size_t)k * N + col];
    } else if (k >= p + npad) {
      int r = k - npad;
      if (r < Ksrc) x = src[(size_t)r * N + col];
    }
    v[j] = (h16)x;
  }
  *(half8*)(dst + (size_t)frag * 512 + (size_t)l * 8) = v;
}

struct Params {
  const float* pts;
  const float* views;
  const h16* wf;
  const float* pb[8];
  const float* views_b;
  const float* feat_b;
  const float* alpha_w;
  const float* alpha_b;
  const float* rgb_w;
  const float* rgb_b;
  float* out;
};

// One 64x256 layer step, 8 waves: wave w owns cols [w*32, w*32+32), rows 0..63
// as two 32x32 tiles. Weights pre-swizzled (MFMA A-slot), activations B-slot ->
// out^T: lane holds m = l&31 (+32*mt), n = w*32 + 8*(r>>2) + (r&3) + 4*(l>>5).
template <int KT, int KT0, bool RELU, bool PRE_BAR>
__device__ __forceinline__ void gemm256(const h16* __restrict__ src0, int ld0,
                                        const h16* __restrict__ src1, int ld1,
                                        const h16* __restrict__ wf,
                                        const float* __restrict__ bias,
                                        h16* __restrict__ dst,
                                        int w, int l) {
  const int lr = l & 31;
  const int lk = (l >> 5) * 8;
  f32x16 acc[2];
  acc[0] = (f32x16)0.f;
  acc[1] = (f32x16)0.f;

#pragma unroll
  for (int kt = 0; kt < KT; ++kt) {
    half8 a[2];
#pragma unroll
    for (int mt = 0; mt < 2; ++mt) {
      const h16* ap;
      if (kt < KT0) ap = src0 + (size_t)(mt * 32 + lr) * ld0 + kt * 16 + lk;
      else          ap = src1 + (size_t)(mt * 32 + lr) * ld1 + (kt - KT0) * 16 + lk;
      a[mt] = *(const half8*)ap;
    }
    half8 b = *(const half8*)(wf + ((size_t)(kt * 8 + w) * 64 + l) * 8);
#pragma unroll
    for (int mt = 0; mt < 2; ++mt)
      acc[mt] = mfma32(b, a[mt], acc[mt]);
  }
  if (PRE_BAR) __syncthreads();
#pragma unroll
  for (int mt = 0; mt < 2; ++mt) {
    int row = mt * 32 + lr;
#pragma unroll
    for (int g = 0; g < 4; ++g) {
      int n0 = w * 32 + g * 8 + (l >> 5) * 4;
      f32x4 bv = *(const f32x4*)(bias + n0);
      half4 pk;
#pragma unroll
      for (int i = 0; i < 4; ++i) {
        float v = acc[mt][g * 4 + i] + bv[i];
        if (RELU) v = fmaxf(v, 0.f);
        pk[i] = (h16)v;
      }
      *(half4*)(dst + (size_t)row * LDH + n0) = pk;
    }
  }
  __syncthreads();
}

__global__ __launch_bounds__(512, 6) void nerf_kernel(Params P) {
  __shared__ __align__(16) h16 ep[64 * LDE];
  __shared__ __align__(16) h16 h[64 * LDH];
  __shared__ __align__(16) h16 evp[32];
  __shared__ float alpha_s[64];

  const int tid = threadIdx.x;
  const int w = tid >> 6, l = tid & 63;
  const int lr = l & 31;
  const int lk = (l >> 5) * 8;
  const int ray = blockIdx.x;

  // ---- stage 0: embeddings (fp32 math, fp16 store) ----
  if (tid < 64) {
    const int s = tid;
    const float x0 = P.pts[((size_t)ray * 64 + s) * 3 + 0];
    const float x1 = P.pts[((size_t)ray * 64 + s) * 3 + 1];
    const float x2 = P.pts[((size_t)ray * 64 + s) * 3 + 2];
    h16* e = ep + (size_t)s * LDE;
    e[0] = (h16)x0; e[1] = (h16)x1; e[2] = (h16)x2;
#pragma unroll
    for (int f = 0; f < 10; ++f) {
      const float sc = (float)(1 << f);
      e[3 + 6 * f + 0] = (h16)sinf(x0 * sc);
      e[3 + 6 * f + 1] = (h16)sinf(x1 * sc);
      e[3 + 6 * f + 2] = (h16)sinf(x2 * sc);
      e[3 + 6 * f + 3] = (h16)cosf(x0 * sc);
      e[3 + 6 * f + 4] = (h16)cosf(x1 * sc);
      e[3 + 6 * f + 5] = (h16)cosf(x2 * sc);
    }
    e[63] = (h16)0.f;  // zero-pad col (weight row 63 is zero too)
  } else if (tid < 96) {
    const int idx = tid - 64;  // 0..31
    float v = 0.f;
    if (idx < 27) {
      if (idx < 3) {
        v = P.views[(size_t)ray * 3 + idx];
      } else {
        const int f = (idx - 3) / 6, rem = (idx - 3) % 6, d = rem % 3;
        const float x = P.views[(size_t)ray * 3 + d] * (float)(1 << f);
        v = (rem < 3) ? sinf(x) : cosf(x);
      }
    }
    evp[idx] = (h16)v;
  }
  __syncthreads();

  // ---- pts MLP trunk (single h buffer, in-place layer updates) ----
  gemm256<4, 4, true, false>(ep, LDE, ep, LDE, P.wf + OFF_P0, P.pb[0], h, w, l);
  gemm256<16, 0, true, true>(ep, LDE, h, LDH, P.wf + OFF_P1, P.pb[1], h, w, l);
  gemm256<16, 0, true, true>(ep, LDE, h, LDH, P.wf + OFF_P2, P.pb[2], h, w, l);
  gemm256<16, 0, true, true>(ep, LDE, h, LDH, P.wf + OFF_P3, P.pb[3], h, w, l);
  gemm256<16, 0, true, true>(ep, LDE, h, LDH, P.wf + OFF_P4, P.pb[4], h, w, l);
  // skip layer: input = [ep(63+pad), h(256)] -> K=320
  gemm256<20, 4, true, true>(ep, LDE, h, LDH, P.wf + OFF_P5, P.pb[5], h, w, l);
  gemm256<16, 0, true, true>(ep, LDE, h, LDH, P.wf + OFF_P6, P.pb[6], h, w, l);
  gemm256<16, 0, true, true>(ep, LDE, h, LDH, P.wf + OFF_P7, P.pb[7], h, w, l);

  // ---- alpha = h @ alpha_w + alpha_b (no relu) ----
  if (tid < 256) {
    const int s = tid >> 2, q = tid & 3;
    float sum = 0.f;
#pragma unroll 8
    for (int k = 0; k < 64; ++k)
      sum += (float)h[(size_t)s * LDH + q * 64 + k] * P.alpha_w[q * 64 + k];
    sum += __shfl_xor(sum, 1);
    sum += __shfl_xor(sum, 2);
    if (q == 0) alpha_s[s] = sum + P.alpha_b[0];
  }

  // ---- feature = h @ feat_w + feat_b (no relu), in place ----
  gemm256<16, 0, false, true>(ep, LDE, h, LDH, P.wf + OFF_FEAT, P.feat_b, h, w, l);

  // ---- h2 = relu([feature, ev] @ views_w + views_b) -> h[:,0..127] ----
  // K = 288 (16 kt from h, 2 kt from broadcast evp), N = 128 on waves 0..3.
  {
    f32x16 acc[2];
    acc[0] = (f32x16)0.f;
    acc[1] = (f32x16)0.f;
    if (w < 4) {
#pragma unroll
      for (int kt = 0; kt < 18; ++kt) {
        half8 a[2];
        if (kt < 16) {
#pragma unroll
          for (int mt = 0; mt < 2; ++mt)
            a[mt] = *(const half8*)(h + (size_t)(mt * 32 + lr) * LDH + kt * 16 + lk);
        } else {
          half8 av = *(const half8*)(evp + (kt - 16) * 16 + lk);  // broadcast row
          a[0] = av; a[1] = av;
        }
        half8 b = *(const half8*)(P.wf + OFF_VIEWS + ((size_t)(kt * 4 + w) * 64 + l) * 8);
#pragma unroll
        for (int mt = 0; mt < 2; ++mt)
          acc[mt] = mfma32(b, a[mt], acc[mt]);
      }
    }
    __syncthreads();  // h is also dst
    if (w < 4) {
#pragma unroll
      for (int mt = 0; mt < 2; ++mt) {
        int row = mt * 32 + lr;
#pragma unroll
        for (int g = 0; g < 4; ++g) {
          int n0 = w * 32 + g * 8 + (l >> 5) * 4;
          f32x4 bv = *(const f32x4*)(P.views_b + n0);
          half4 pk;
#pragma unroll
          for (int i = 0; i < 4; ++i)
            pk[i] = (h16)fmaxf(acc[mt][g * 4 + i] + bv[i], 0.f);
          *(half4*)(h + (size_t)row * LDH + n0) = pk;
        }
      }
    }
    __syncthreads();
  }

  // ---- rgb + output ----
  if (tid < 256) {
    const int s = tid >> 2, q = tid & 3;
    float r0 = 0.f, r1 = 0.f, r2 = 0.f;
#pragma unroll 8
    for (int k = 0; k < 32; ++k) {
      const int kk = q * 32 + k;
      const float hv = (float)h[(size_t)s * LDH + kk];
      r0 += hv * P.rgb_w[kk * 3 + 0];
      r1 += hv * P.rgb_w[kk * 3 + 1];
      r2 += hv * P.rgb_w[kk * 3 + 2];
    }
    r0 += __shfl_xor(r0, 1); r0 += __shfl_xor(r0, 2);
    r1 += __shfl_xor(r1, 1); r1 += __shfl_xor(r1, 2);
    r2 += __shfl_xor(r2, 1); r2 += __shfl_xor(r2, 2);
    if (q == 0) {
      float4 o;
      o.x = r0 + P.rgb_b[0];
      o.y = r1 + P.rgb_b[1];
      o.z = r2 + P.rgb_b[2];
      o.w = alpha_s[s];
      *(float4*)(P.out + ((size_t)ray * 64 + s) * 4) = o;
    }
  }
}

extern "C" void kernel_launch(void* const* d_in, const int* in_sizes, int n_in,
                              void* d_out, int out_size, void* d_ws, size_t ws_size,
                              hipStream_t stream) {
  h16* wsw = (h16*)d_ws;
  auto conv = [&](int idx, int Ksrc, int N, int Kp, int p, int npad, size_t off) {
    int nfrags = (Kp / 16) * (N / 32);
    int total = nfrags * 64;
    convw_kernel<<<(total + 255) / 256, 256, 0, stream>>>(
        (const float*)d_in[idx], wsw + off, Ksrc, N, Kp, p, npad);
  };
  conv(2, 63, 256, 64, 63, 1, OFF_P0);
  conv(4, 256, 256, 256, 256, 0, OFF_P1);
  conv(6, 256, 256, 256, 256, 0, OFF_P2);
  conv(8, 256, 256, 256, 256, 0, OFF_P3);
  conv(10, 256, 256, 256, 256, 0, OFF_P4);
  conv(12, 319, 256, 320, 63, 1, OFF_P5);
  conv(14, 256, 256, 256, 256, 0, OFF_P6);
  conv(16, 256, 256, 256, 256, 0, OFF_P7);
  conv(20, 256, 256, 256, 256, 0, OFF_FEAT);
  conv(18, 283, 128, 288, 283, 5, OFF_VIEWS);

  Params P;
  P.pts = (const float*)d_in[0];
  P.views = (const float*)d_in[1];
  P.wf = wsw;
  for (int i = 0; i < 8; ++i) P.pb[i] = (const float*)d_in[3 + 2 * i];
  P.views_b = (const float*)d_in[19];
  P.feat_b = (const float*)d_in[21];
  P.alpha_w = (const float*)d_in[22];
  P.alpha_b = (const float*)d_in[23];
  P.rgb_w = (const float*)d_in[24];
  P.rgb_b = (const float*)d_in[25];
  P.out = (float*)d_out;

  nerf_kernel<<<4096, 512, 0, stream>>>(P);
}